// Round 5
// baseline (176.739 us; speedup 1.0000x reference)
//
#include <hip/hip_runtime.h>

// B=2, T=2048, C=1024, H=16, HD=64, SCALE=0.125
// Pipeline: cvt x->bf16; transpose W->bf16 [N][K]; GEMM1 qkv=x@Wqkv (bf16 out,
// Q cols pre-scaled by SCALE*log2e); transpose V part -> vT; flash attn v5
// (barrier-free 1-wave blocks, K/V direct from L2, swapped-QK^T, O^T accum,
// paired subtiles j/127-j, exp2 softmax, cvt_pk, defer-max) -> att (bf16);
// GEMM2 out = att@Wp + bp (f32).

typedef __attribute__((ext_vector_type(8))) short shortx8;
typedef __attribute__((ext_vector_type(4))) short shortx4;
typedef __attribute__((ext_vector_type(8))) unsigned short ushortx8;
typedef __attribute__((ext_vector_type(4))) float f32x4;

#define MFMA16(a, b, c) __builtin_amdgcn_mfma_f32_16x16x32_bf16((a), (b), (c), 0, 0, 0)

// SCALE * log2(e): softmax done in exp2 domain; folded into Q at GEMM1 epilogue
#define SC_L2E 0.18033688011112042f

__device__ __forceinline__ unsigned short f2bf(float f) {
  union { float f; unsigned u; } v; v.f = f;
  unsigned r = v.u + 0x7fffu + ((v.u >> 16) & 1u);  // RNE; inputs finite
  return (unsigned short)(r >> 16);
}

__device__ __forceinline__ float fexp2(float x) {
#if __has_builtin(__builtin_amdgcn_exp2f)
  return __builtin_amdgcn_exp2f(x);
#else
  return exp2f(x);
#endif
}

__device__ __forceinline__ void gload16(const void* g, void* l) {
  __builtin_amdgcn_global_load_lds(
      (const __attribute__((address_space(1))) void*)g,
      (__attribute__((address_space(3))) void*)l, 16, 0, 0);
}

// ---------------- conversions ----------------
__global__ __launch_bounds__(256) void cvt_x(const float* __restrict__ x,
                                             unsigned short* __restrict__ xb, int n4) {
  int i = blockIdx.x * 256 + threadIdx.x;
  if (i < n4) {
    float4 v = ((const float4*)x)[i];
    unsigned short* o = xb + (size_t)i * 4;
    o[0] = f2bf(v.x); o[1] = f2bf(v.y); o[2] = f2bf(v.z); o[3] = f2bf(v.w);
  }
}

// 4x W [1024][1024] f32 -> WT [1024][1024] bf16 (WT[n][k] = W[k][n]); z picks matrix
__global__ __launch_bounds__(256) void transpose_w4(
    const float* __restrict__ Wq, const float* __restrict__ Wk,
    const float* __restrict__ Wv, const float* __restrict__ Wp,
    unsigned short* __restrict__ wqkvT, unsigned short* __restrict__ wpT) {
  __shared__ float tile[32][33];
  const int zi = blockIdx.z;
  const float* src = (zi == 0) ? Wq : (zi == 1) ? Wk : (zi == 2) ? Wv : Wp;
  unsigned short* dst = (zi == 3) ? wpT : wqkvT + (size_t)zi * 1048576;
  const int bx = blockIdx.x * 32, by = blockIdx.y * 32;
  const int tx = threadIdx.x & 31, ty = threadIdx.x >> 5;  // 32 x 8
  #pragma unroll
  for (int i = 0; i < 32; i += 8)
    tile[ty + i][tx] = src[(size_t)(by + ty + i) * 1024 + bx + tx];
  __syncthreads();
  #pragma unroll
  for (int i = 0; i < 32; i += 8)
    dst[(size_t)(bx + ty + i) * 1024 + by + tx] = f2bf(tile[tx][ty + i]);
}

// V part of qkv [4096][cols 2048..3071] bf16 -> vT [1024][4096] bf16
__global__ __launch_bounds__(256) void transpose_v(const unsigned short* __restrict__ qkv,
                                                   unsigned short* __restrict__ vT) {
  __shared__ unsigned short tile[64][65];
  const int bx = blockIdx.x * 64;  // hd dim (0..1023)
  const int by = blockIdx.y * 64;  // row dim (0..4095)
  const int t = threadIdx.x;
  const int r = t >> 3, c8 = (t & 7) << 3;
  #pragma unroll
  for (int i = 0; i < 2; ++i) {
    ushortx8 v = *(const ushortx8*)&qkv[(size_t)(by + i * 32 + r) * 3072 + 2048 + bx + c8];
    #pragma unroll
    for (int j = 0; j < 8; ++j) tile[i * 32 + r][c8 + j] = v[j];
  }
  __syncthreads();
  #pragma unroll
  for (int i = 0; i < 2; ++i) {
    const int dr = i * 32 + r;
    ushortx8 o;
    #pragma unroll
    for (int j = 0; j < 8; ++j) o[j] = tile[c8 + j][dr];
    *(ushortx8*)&vT[(size_t)(bx + dr) * 4096 + by + c8] = o;
  }
}

// ---------------- GEMM: C[M,N] = A[M,K] @ BT[N,K]^T ----------------
// qscale applied to bf16 output cols < scale_cols (folds attn scale into Q).
__global__ __launch_bounds__(256) void gemm_bt(
    const unsigned short* __restrict__ A, const unsigned short* __restrict__ BT,
    unsigned short* __restrict__ Cb, float* __restrict__ Cf,
    const float* __restrict__ bias, int M, int N, int K,
    float qscale, int scale_cols) {
  __shared__ unsigned short As[128 * 32];
  __shared__ unsigned short Bs[128 * 32];
  const int tid = threadIdx.x;
  const int lane = tid & 63, w = tid >> 6;
  const int wr = w >> 1, wc = w & 1;
  const int brow = blockIdx.y << 7, bcol = blockIdx.x << 7;

  f32x4 z = {0.f, 0.f, 0.f, 0.f};
  f32x4 acc[4][4];
  #pragma unroll
  for (int m = 0; m < 4; ++m)
    #pragma unroll
    for (int n = 0; n < 4; ++n) acc[m][n] = z;

  const int srow = tid >> 2;
  const int scol = (tid & 3) << 3;
  const unsigned short* Ap = A + (size_t)(brow + srow) * K + scol;
  const unsigned short* Bp = BT + (size_t)(bcol + srow) * K + scol;
  unsigned short* AsW = &As[w * 512];
  unsigned short* BsW = &Bs[w * 512];
  const size_t rowK64 = (size_t)64 * K;

  for (int k0 = 0; k0 < K; k0 += 32) {
    gload16(Ap + k0, AsW);
    gload16(Ap + rowK64 + k0, AsW + 2048);
    gload16(Bp + k0, BsW);
    gload16(Bp + rowK64 + k0, BsW + 2048);
    __syncthreads();
    shortx8 af[4], bf[4];
    const int koff = (lane >> 4) << 3;
    const int ar = (wr << 6) + (lane & 15);
    const int br = (wc << 6) + (lane & 15);
    #pragma unroll
    for (int m = 0; m < 4; ++m) af[m] = *(const shortx8*)&As[(ar + m * 16) * 32 + koff];
    #pragma unroll
    for (int n = 0; n < 4; ++n) bf[n] = *(const shortx8*)&Bs[(br + n * 16) * 32 + koff];
    #pragma unroll
    for (int m = 0; m < 4; ++m)
      #pragma unroll
      for (int n = 0; n < 4; ++n) acc[m][n] = MFMA16(af[m], bf[n], acc[m][n]);
    __syncthreads();
  }

  const int r0 = (lane >> 4) << 2;
  const int c0 = lane & 15;
  if (Cb) {
    #pragma unroll
    for (int m = 0; m < 4; ++m)
      #pragma unroll
      for (int n = 0; n < 4; ++n)
        #pragma unroll
        for (int j = 0; j < 4; ++j) {
          const size_t row = brow + (wr << 6) + m * 16 + r0 + j;
          const size_t col = bcol + (wc << 6) + n * 16 + c0;
          float v = acc[m][n][j];
          if ((int)col < scale_cols) v *= qscale;
          Cb[row * N + col] = f2bf(v);
        }
  } else {
    #pragma unroll
    for (int m = 0; m < 4; ++m)
      #pragma unroll
      for (int n = 0; n < 4; ++n)
        #pragma unroll
        for (int j = 0; j < 4; ++j) {
          const size_t row = brow + (wr << 6) + m * 16 + r0 + j;
          const size_t col = bcol + (wc << 6) + n * 16 + c0;
          Cf[row * N + col] = acc[m][n][j] + bias[col];
        }
  }
}

// ---------------- flash attention v5 ----------------
// 1 wave/block (64 thr), barrier-free. Wave owns q-subtiles j (near) and 127-j
// (far) of one (b,h) stream -> ~33 sub-computations/wave, uniform. K and V^T
// fragments read DIRECTLY from global (L2-resident; XCD-affine grid keeps each
// stream's 512 KB K/V on one XCD's L2). Swapped QK^T (S^T per-lane softmax),
// O^T = mfma(V^T, P^T). Only LDS use: 4 KB Ps for P^T -> B-operand relayout.

__device__ __forceinline__ void softmax_pack(
    const f32x4* s, unsigned short* PsS, int ql, int g, int kv0, int qrow,
    bool mask, float& m_run, float& l_run, f32x4* acc) {
  float sv[16];
  #pragma unroll
  for (int f = 0; f < 4; ++f)
    #pragma unroll
    for (int j = 0; j < 4; ++j) sv[f * 4 + j] = s[f][j];  // pre-scaled via Q
  if (mask) {
    #pragma unroll
    for (int f = 0; f < 4; ++f)
      #pragma unroll
      for (int j = 0; j < 4; ++j)
        if (kv0 + 16 * f + 4 * g + j > qrow) sv[f * 4 + j] = -__builtin_inff();
  }
  float m8[8], m4[4];
  #pragma unroll
  for (int i = 0; i < 8; ++i) m8[i] = fmaxf(sv[2 * i], sv[2 * i + 1]);
  #pragma unroll
  for (int i = 0; i < 4; ++i) m4[i] = fmaxf(m8[2 * i], m8[2 * i + 1]);
  float mx = fmaxf(fmaxf(m4[0], m4[1]), fmaxf(m4[2], m4[3]));
  mx = fmaxf(mx, __shfl_xor(mx, 16));
  mx = fmaxf(mx, __shfl_xor(mx, 32));

  if (!__all(mx <= m_run + 8.0f)) {  // defer-max: P bounded by 2^8
    const float nm = fmaxf(m_run, mx);
    const float alpha = fexp2(m_run - nm);
    #pragma unroll
    for (int c = 0; c < 4; ++c) acc[c] *= alpha;
    l_run *= alpha;
    m_run = nm;
  }

  float p[16];
  #pragma unroll
  for (int i = 0; i < 16; ++i) p[i] = fexp2(sv[i] - m_run);
  float s8[8], s4[4];
  #pragma unroll
  for (int i = 0; i < 8; ++i) s8[i] = p[2 * i] + p[2 * i + 1];
  #pragma unroll
  for (int i = 0; i < 4; ++i) s4[i] = s8[2 * i] + s8[2 * i + 1];
  float rsum = (s4[0] + s4[1]) + (s4[2] + s4[3]);
  rsum += __shfl_xor(rsum, 16);
  rsum += __shfl_xor(rsum, 32);
  l_run += rsum;

  // P^T -> Ps chunk-major [chunk8][ql16][8e]; lane holds kv 16f+4g+j
  #pragma unroll
  for (int f = 0; f < 4; ++f) {
    unsigned lo, hi;
    asm("v_cvt_pk_bf16_f32 %0, %1, %2" : "=v"(lo) : "v"(p[4 * f + 0]), "v"(p[4 * f + 1]));
    asm("v_cvt_pk_bf16_f32 %0, %1, %2" : "=v"(hi) : "v"(p[4 * f + 2]), "v"(p[4 * f + 3]));
    uint2 u; u.x = lo; u.y = hi;
    *(uint2*)&PsS[(2 * f + (g >> 1)) * 128 + ql * 8 + (g & 1) * 4] = u;
  }
}

__global__ __launch_bounds__(64) void attn_fwd(
    const unsigned short* __restrict__ qkv, const unsigned short* __restrict__ vT,
    unsigned short* __restrict__ att) {
  __shared__ unsigned short Ps[2][1024];  // [sub][chunk8*16ql*8e] = 4 KB

  const int lane = threadIdx.x;
  const int stream = blockIdx.x;          // consecutive ids = different streams
  const int h = stream & 15, b = stream >> 4;
  const int j = blockIdx.y;               // pair index 0..63
  const int ql = lane & 15, g = lane >> 4;
  const int qrowA = 16 * j + ql;          // near-diagonal subtile
  const int qrowB = 16 * (127 - j) + ql;  // far subtile
  const int dA = j >> 2;                  // A's diagonal kv tile
  const int dB = (127 - j) >> 2;          // B's diagonal kv tile (> dA always)

  // Q fragments (MFMA B-operand): Q[q=ql][d=8g+e]; pre-scaled by SC_L2E
  const unsigned short* qpA = qkv + ((size_t)(b * 2048 + qrowA)) * 3072 + h * 64 + (g << 3);
  const unsigned short* qpB = qkv + ((size_t)(b * 2048 + qrowB)) * 3072 + h * 64 + (g << 3);
  const shortx8 qfA0 = *(const shortx8*)qpA;
  const shortx8 qfA1 = *(const shortx8*)(qpA + 32);
  const shortx8 qfB0 = *(const shortx8*)qpB;
  const shortx8 qfB1 = *(const shortx8*)(qpB + 32);

  f32x4 z = {0.f, 0.f, 0.f, 0.f};
  f32x4 accA[4], accB[4];
  #pragma unroll
  for (int c = 0; c < 4; ++c) { accA[c] = z; accB[c] = z; }
  float mA = -__builtin_inff(), lA = 0.f, mB = -__builtin_inff(), lB = 0.f;

  // direct-global fragment bases
  const unsigned short* kbase = qkv + ((size_t)(b * 2048 + ql)) * 3072 + 1024 + h * 64 + (g << 3);
  const unsigned short* vbase = vT + ((size_t)(h * 64 + ql)) * 4096 + b * 2048 + (g << 3);

  for (int kvt = 0; kvt <= dB; ++kvt) {
    const int kv0 = kvt << 6;
    const bool actA = (kvt <= dA);

    // K fragments direct from L2: rows kv0+16f+ql, d-halves 0..31 / 32..63
    shortx8 kf0[4], kf1[4];
    #pragma unroll
    for (int f = 0; f < 4; ++f) {
      const unsigned short* kp = kbase + (size_t)(kv0 + 16 * f) * 3072;
      kf0[f] = *(const shortx8*)kp;
      kf1[f] = *(const shortx8*)(kp + 32);
    }
    // QK^T (B always; A while active)
    f32x4 sB[4];
    #pragma unroll
    for (int f = 0; f < 4; ++f) {
      f32x4 t = MFMA16(kf0[f], qfB0, z);
      sB[f] = MFMA16(kf1[f], qfB1, t);
    }
    f32x4 sA[4];
    if (actA) {
      #pragma unroll
      for (int f = 0; f < 4; ++f) {
        f32x4 t = MFMA16(kf0[f], qfA0, z);
        sA[f] = MFMA16(kf1[f], qfA1, t);
      }
    }
    // V^T fragments direct from L2 (latency hides under softmax)
    shortx8 vf0[4], vf1[4];
    #pragma unroll
    for (int c = 0; c < 4; ++c) {
      const unsigned short* vp = vbase + (size_t)(16 * c) * 4096 + kv0;
      vf0[c] = *(const shortx8*)vp;
      vf1[c] = *(const shortx8*)(vp + 32);
    }

    if (actA) {
      softmax_pack(sA, &Ps[0][0], ql, g, kv0, qrowA, kvt == dA, mA, lA, accA);
      __builtin_amdgcn_sched_barrier(0);  // same-wave DS write before read
      shortx8 pf0 = *(const shortx8*)&Ps[0][(g) * 128 + ql * 8];
      shortx8 pf1 = *(const shortx8*)&Ps[0][(4 + g) * 128 + ql * 8];
      __builtin_amdgcn_sched_barrier(0);
      #pragma unroll
      for (int c = 0; c < 4; ++c) {
        accA[c] = MFMA16(vf0[c], pf0, accA[c]);
        accA[c] = MFMA16(vf1[c], pf1, accA[c]);
      }
    }
    {
      softmax_pack(sB, &Ps[1][0], ql, g, kv0, qrowB, kvt == dB, mB, lB, accB);
      __builtin_amdgcn_sched_barrier(0);
      shortx8 pf0 = *(const shortx8*)&Ps[1][(g) * 128 + ql * 8];
      shortx8 pf1 = *(const shortx8*)&Ps[1][(4 + g) * 128 + ql * 8];
      __builtin_amdgcn_sched_barrier(0);
      #pragma unroll
      for (int c = 0; c < 4; ++c) {
        accB[c] = MFMA16(vf0[c], pf0, accB[c]);
        accB[c] = MFMA16(vf1[c], pf1, accB[c]);
      }
    }
  }

  // epilogue: acc[c][j] = O^T[d=16c+4g+j][q=qrow]; pack 4 consecutive d -> 8B store
  const float invA = 1.f / lA;
  const float invB = 1.f / lB;
  unsigned short* oA = att + ((size_t)(b * 2048 + qrowA)) * 1024 + h * 64 + 4 * g;
  unsigned short* oB = att + ((size_t)(b * 2048 + qrowB)) * 1024 + h * 64 + 4 * g;
  #pragma unroll
  for (int c = 0; c < 4; ++c) {
    shortx4 a, bb;
    #pragma unroll
    for (int jj = 0; jj < 4; ++jj) {
      a[jj] = (short)f2bf(accA[c][jj] * invA);
      bb[jj] = (short)f2bf(accB[c][jj] * invB);
    }
    *(shortx4*)&oA[16 * c] = a;
    *(shortx4*)&oB[16 * c] = bb;
  }
}

// ---------------- launch ----------------
extern "C" void kernel_launch(void* const* d_in, const int* in_sizes, int n_in,
                              void* d_out, int out_size, void* d_ws, size_t ws_size,
                              hipStream_t stream) {
  const float* x  = (const float*)d_in[0];
  const float* Wq = (const float*)d_in[1];
  const float* Wk = (const float*)d_in[2];
  const float* Wv = (const float*)d_in[3];
  const float* Wp = (const float*)d_in[4];
  const float* bp = (const float*)d_in[5];

  char* ws = (char*)d_ws;
  unsigned short* xb    = (unsigned short*)(ws);                        //  8 MB [4096][1024]
  unsigned short* wqkvT = (unsigned short*)(ws + (size_t)8  * 1048576); //  6 MB [3072][1024]
  unsigned short* wpT   = (unsigned short*)(ws + (size_t)14 * 1048576); //  2 MB [1024][1024]
  unsigned short* qkv   = (unsigned short*)(ws + (size_t)16 * 1048576); // 24 MB [4096][3072]
  unsigned short* vT    = (unsigned short*)(ws + (size_t)40 * 1048576); //  8 MB [1024][4096]
  unsigned short* att   = (unsigned short*)(ws + (size_t)48 * 1048576); //  8 MB [4096][1024]

  cvt_x<<<dim3(4096), dim3(256), 0, stream>>>(x, xb, 1048576);
  transpose_w4<<<dim3(32, 32, 4), dim3(256), 0, stream>>>(Wq, Wk, Wv, Wp, wqkvT, wpT);
  gemm_bt<<<dim3(24, 32), dim3(256), 0, stream>>>(xb, wqkvT, qkv, nullptr, nullptr,
                                                  4096, 3072, 1024, SC_L2E, 1024);
  transpose_v<<<dim3(16, 64), dim3(256), 0, stream>>>(qkv, vT);
  attn_fwd<<<dim3(32, 64), dim3(64), 0, stream>>>(qkv, vT, att);
  gemm_bt<<<dim3(8, 32), dim3(256), 0, stream>>>(att, wpT, nullptr, (float*)d_out, bp,
                                                 4096, 1024, 1024, 0.f, 0);
}